// Round 1
// baseline (1541.514 us; speedup 1.0000x reference)
//
#include <hip/hip_runtime.h>

#define SLOPE 0.2f

// ---- order-preserving float<->uint key for atomicMax-based segment max ----
__device__ __forceinline__ unsigned int fkey(float v) {
    unsigned int ui = __float_as_uint(v);
    return (ui & 0x80000000u) ? ~ui : (ui | 0x80000000u);
}
__device__ __forceinline__ float funkey(unsigned int k) {
    unsigned int ui = (k & 0x80000000u) ? (k & 0x7fffffffu) : ~k;
    return __uint_as_float(ui);
}

// xp = x @ W  (in_dim -> 128 = 2 heads * 64), plus per-head attention dots.
// One block (128 threads = 2 waves) per node; wave h reduces head h.
__global__ void k_xp_att(const float* __restrict__ x, const float* __restrict__ W,
                         const float* __restrict__ as_, const float* __restrict__ ad_,
                         float* __restrict__ xp, float* __restrict__ asrc,
                         float* __restrict__ adst, int in_dim) {
    int n = blockIdx.x;
    int c = threadIdx.x;               // 0..127
    __shared__ float xr[64];
    if (c < in_dim) xr[c] = x[(size_t)n * in_dim + c];
    __syncthreads();
    float acc = 0.f;
    for (int k = 0; k < in_dim; ++k) acc += xr[k] * W[k * 128 + c];
    xp[(size_t)n * 128 + c] = acc;
    int h = c >> 6, ch = c & 63;
    float ps = acc * as_[h * 64 + ch];
    float pd = acc * ad_[h * 64 + ch];
    for (int off = 32; off > 0; off >>= 1) {
        ps += __shfl_down(ps, off, 64);
        pd += __shfl_down(pd, off, 64);
    }
    if (ch == 0) { asrc[n * 2 + h] = ps; adst[n * 2 + h] = pd; }
}

// Segment max over incoming edges (incl. self-loops), one thread per (edge, head).
__global__ void k_edge_max(const int* __restrict__ src, const int* __restrict__ dst,
                           const float* __restrict__ asrc, const float* __restrict__ adst,
                           unsigned int* __restrict__ emax, int E, int Et) {
    int i = blockIdx.x * blockDim.x + threadIdx.x;
    if (i >= Et * 2) return;
    int e = i >> 1, h = i & 1;
    int s, d;
    if (e < E) { s = src[e]; d = dst[e]; } else { s = e - E; d = s; }
    float v = asrc[s * 2 + h] + adst[d * 2 + h];
    v = v >= 0.f ? v : SLOPE * v;
    atomicMax(&emax[d * 2 + h], fkey(v));
}

// Segment sum of exp(e - max).
__global__ void k_edge_den(const int* __restrict__ src, const int* __restrict__ dst,
                           const float* __restrict__ asrc, const float* __restrict__ adst,
                           const unsigned int* __restrict__ emax, float* __restrict__ den,
                           int E, int Et) {
    int i = blockIdx.x * blockDim.x + threadIdx.x;
    if (i >= Et * 2) return;
    int e = i >> 1, h = i & 1;
    int s, d;
    if (e < E) { s = src[e]; d = dst[e]; } else { s = e - E; d = s; }
    float v = asrc[s * 2 + h] + adst[d * 2 + h];
    v = v >= 0.f ? v : SLOPE * v;
    float ex = __expf(v - funkey(emax[d * 2 + h]));
    atomicAdd(&den[d * 2 + h], ex);
}

// Message aggregation: one 128-thread block per edge, scatter-add 128 channels.
__global__ void k_edge_agg(const int* __restrict__ src, const int* __restrict__ dst,
                           const float* __restrict__ asrc, const float* __restrict__ adst,
                           const unsigned int* __restrict__ emax, const float* __restrict__ den,
                           const float* __restrict__ xp, float* __restrict__ agg, int E) {
    int e = blockIdx.x;
    int s, d;
    if (e < E) { s = src[e]; d = dst[e]; } else { s = e - E; d = s; }
    int c = threadIdx.x, h = c >> 6;
    float v = asrc[s * 2 + h] + adst[d * 2 + h];
    v = v >= 0.f ? v : SLOPE * v;
    float alpha = __expf(v - funkey(emax[d * 2 + h])) / (den[d * 2 + h] + 1e-16f);
    atomicAdd(&agg[(size_t)d * 128 + c], xp[(size_t)s * 128 + c] * alpha);
}

// Head-mean + bias + ReLU -> h [N,64]
__global__ void k_relu_mean(const float* __restrict__ agg, const float* __restrict__ b,
                            float* __restrict__ hout, int n64) {
    int i = blockIdx.x * blockDim.x + threadIdx.x;
    if (i >= n64) return;
    int n = i >> 6, c = i & 63;
    float v = (agg[(size_t)n * 128 + c] + agg[(size_t)n * 128 + 64 + c]) * 0.5f + b[c];
    hout[i] = v > 0.f ? v : 0.f;
}

// climber embed: relu(climber @ Wc + bc), [G,64]
__global__ void k_climber(const float* __restrict__ climber, const float* __restrict__ Wc,
                          const float* __restrict__ bc, float* __restrict__ cemb, int g64) {
    int i = blockIdx.x * blockDim.x + threadIdx.x;
    if (i >= g64) return;
    int g = i >> 6, c = i & 63;
    float acc = bc[c];
    for (int k = 0; k < 4; ++k) acc += climber[g * 4 + k] * Wc[k * 64 + c];
    cemb[i] = acc > 0.f ? acc : 0.f;
}

// final: z=[h2, cemb[batch]] (128) -> relu(z@Wm1+bm1) (64) -> @Wm2+bm2 (4)
__global__ void k_final(const float* __restrict__ h2, const float* __restrict__ cemb,
                        const int* __restrict__ batch, const float* __restrict__ Wm1,
                        const float* __restrict__ bm1, const float* __restrict__ Wm2,
                        const float* __restrict__ bm2, float* __restrict__ out) {
    int n = blockIdx.x, t = threadIdx.x;   // 64 threads
    __shared__ float z[128];
    __shared__ float mbuf[64];
    z[t] = h2[(size_t)n * 64 + t];
    z[64 + t] = cemb[(size_t)batch[n] * 64 + t];
    __syncthreads();
    float acc = bm1[t];
    for (int k = 0; k < 128; ++k) acc += z[k] * Wm1[k * 64 + t];
    mbuf[t] = acc > 0.f ? acc : 0.f;
    __syncthreads();
    if (t < 4) {
        float o = bm2[t];
        for (int k = 0; k < 64; ++k) o += mbuf[k] * Wm2[k * 4 + t];
        out[(size_t)n * 4 + t] = o;
    }
}

extern "C" void kernel_launch(void* const* d_in, const int* in_sizes, int n_in,
                              void* d_out, int out_size, void* d_ws, size_t ws_size,
                              hipStream_t stream) {
    const float* x       = (const float*)d_in[0];
    const int*   ei      = (const int*)  d_in[1];
    const int*   batch   = (const int*)  d_in[2];
    const float* climber = (const float*)d_in[3];
    const float* W1  = (const float*)d_in[4];
    const float* as1 = (const float*)d_in[5];
    const float* ad1 = (const float*)d_in[6];
    const float* b1  = (const float*)d_in[7];
    const float* W2  = (const float*)d_in[8];
    const float* as2 = (const float*)d_in[9];
    const float* ad2 = (const float*)d_in[10];
    const float* b2  = (const float*)d_in[11];
    const float* Wc  = (const float*)d_in[12];
    const float* bc  = (const float*)d_in[13];
    const float* Wm1 = (const float*)d_in[14];
    const float* bm1 = (const float*)d_in[15];
    const float* Wm2 = (const float*)d_in[16];
    const float* bm2 = (const float*)d_in[17];

    const int N  = in_sizes[0] / 6;
    const int E  = in_sizes[1] / 2;
    const int G  = in_sizes[3] / 4;
    const int Et = E + N;

    const int* srcI = ei;
    const int* dstI = ei + E;

    float* ws = (float*)d_ws;
    size_t off = 0;
    float*        xp   = ws + off; off += (size_t)N * 128;
    float*        agg  = ws + off; off += (size_t)N * 128;
    float*        asrc = ws + off; off += (size_t)N * 2;
    float*        adst = ws + off; off += (size_t)N * 2;
    unsigned int* emax = (unsigned int*)(ws + off); off += (size_t)N * 2;
    float*        den  = ws + off; off += (size_t)N * 2;   // emax..den contiguous
    float*        hbuf = ws + off; off += (size_t)N * 64;
    float*        cemb = ws + off; off += (size_t)G * 64;

    const int tpb = 256;
    const int gEdge = (Et * 2 + tpb - 1) / tpb;

    // ---------------- layer 1 ----------------
    k_xp_att<<<N, 128, 0, stream>>>(x, W1, as1, ad1, xp, asrc, adst, 6);
    hipMemsetAsync(emax, 0, (size_t)N * 4 * sizeof(float), stream);      // emax(key 0 = -inf) + den
    hipMemsetAsync(agg,  0, (size_t)N * 128 * sizeof(float), stream);
    k_edge_max<<<gEdge, tpb, 0, stream>>>(srcI, dstI, asrc, adst, emax, E, Et);
    k_edge_den<<<gEdge, tpb, 0, stream>>>(srcI, dstI, asrc, adst, emax, den, E, Et);
    k_edge_agg<<<Et, 128, 0, stream>>>(srcI, dstI, asrc, adst, emax, den, xp, agg, E);
    k_relu_mean<<<(N * 64 + tpb - 1) / tpb, tpb, 0, stream>>>(agg, b1, hbuf, N * 64);

    // ---------------- layer 2 ----------------
    k_xp_att<<<N, 128, 0, stream>>>(hbuf, W2, as2, ad2, xp, asrc, adst, 64);
    hipMemsetAsync(emax, 0, (size_t)N * 4 * sizeof(float), stream);
    hipMemsetAsync(agg,  0, (size_t)N * 128 * sizeof(float), stream);
    k_edge_max<<<gEdge, tpb, 0, stream>>>(srcI, dstI, asrc, adst, emax, E, Et);
    k_edge_den<<<gEdge, tpb, 0, stream>>>(srcI, dstI, asrc, adst, emax, den, E, Et);
    k_edge_agg<<<Et, 128, 0, stream>>>(srcI, dstI, asrc, adst, emax, den, xp, agg, E);
    k_relu_mean<<<(N * 64 + tpb - 1) / tpb, tpb, 0, stream>>>(agg, b2, hbuf, N * 64);

    // ---------------- classifier ----------------
    k_climber<<<(G * 64 + tpb - 1) / tpb, tpb, 0, stream>>>(climber, Wc, bc, cemb, G * 64);
    k_final<<<N, 64, 0, stream>>>(hbuf, cemb, batch, Wm1, bm1, Wm2, bm2, (float*)d_out);
}

// Round 2
// 836.000 us; speedup vs baseline: 1.8439x; 1.8439x over previous
//
#include <hip/hip_runtime.h>

#define SLOPE 0.2f

__device__ __forceinline__ float lrelu(float v) { return v >= 0.f ? v : SLOPE * v; }

// ============================================================================
// xp = x @ W  (in_dim -> 128 = 2 heads * 64), plus per-head attention dots.
// One block (128 threads = 2 waves) per node; wave h reduces head h.
// ============================================================================
__global__ void k_xp_att(const float* __restrict__ x, const float* __restrict__ W,
                         const float* __restrict__ as_, const float* __restrict__ ad_,
                         float* __restrict__ xp, float* __restrict__ asrc,
                         float* __restrict__ adst, int in_dim) {
    int n = blockIdx.x;
    int c = threadIdx.x;               // 0..127
    __shared__ float xr[64];
    if (c < in_dim) xr[c] = x[(size_t)n * in_dim + c];
    __syncthreads();
    float acc = 0.f;
    for (int k = 0; k < in_dim; ++k) acc += xr[k] * W[k * 128 + c];
    xp[(size_t)n * 128 + c] = acc;
    int h = c >> 6, ch = c & 63;
    float ps = acc * as_[h * 64 + ch];
    float pd = acc * ad_[h * 64 + ch];
    for (int off = 32; off > 0; off >>= 1) {
        ps += __shfl_down(ps, off, 64);
        pd += __shfl_down(pd, off, 64);
    }
    if (ch == 0) { asrc[n * 2 + h] = ps; adst[n * 2 + h] = pd; }
}

// ============================================================================
// CSR build: histogram -> exclusive scan -> scatter (counting sort by dst)
// ============================================================================
__global__ void k_hist(const int* __restrict__ dst, int* __restrict__ deg, int E) {
    for (int e = blockIdx.x * blockDim.x + threadIdx.x; e < E; e += gridDim.x * blockDim.x)
        atomicAdd(&deg[dst[e]], 1);
}

// pass 1: per-block (1024 elements) partial sums
__global__ void k_scan_partial(const int* __restrict__ deg, int* __restrict__ partial, int N) {
    int b = blockIdx.x, t = threadIdx.x;
    int base = b * 1024 + t * 4;
    int s = 0;
    for (int i = 0; i < 4; ++i) { int idx = base + i; if (idx < N) s += deg[idx]; }
    __shared__ int sh[256];
    sh[t] = s; __syncthreads();
    for (int off = 128; off > 0; off >>= 1) { if (t < off) sh[t] += sh[t + off]; __syncthreads(); }
    if (t == 0) partial[b] = sh[0];
}

// pass 2: single-block exclusive scan of partials (chunked, robust to any nb)
__global__ void k_scan_partials(int* __restrict__ partial, int nb) {
    __shared__ int sh[256];
    __shared__ int carry;
    int t = threadIdx.x;
    if (t == 0) carry = 0;
    __syncthreads();
    for (int base = 0; base < nb; base += 256) {
        int idx = base + t;
        int orig = (idx < nb) ? partial[idx] : 0;
        sh[t] = orig; __syncthreads();
        for (int off = 1; off < 256; off <<= 1) {
            int v = (t >= off) ? sh[t - off] : 0;
            __syncthreads();
            sh[t] += v;
            __syncthreads();
        }
        if (idx < nb) partial[idx] = carry + sh[t] - orig;
        __syncthreads();
        if (t == 0) carry += sh[255];
        __syncthreads();
    }
}

// pass 3: in-block exclusive scan + partial offset -> rowptr
__global__ void k_scan_final(const int* __restrict__ deg, const int* __restrict__ partial,
                             int* __restrict__ rowptr, int N, int E) {
    int b = blockIdx.x, t = threadIdx.x;
    int base = b * 1024 + t * 4;
    int local[4]; int s = 0;
    for (int i = 0; i < 4; ++i) { int idx = base + i; local[i] = (idx < N) ? deg[idx] : 0; s += local[i]; }
    __shared__ int sh[256];
    int orig = s;
    sh[t] = s; __syncthreads();
    for (int off = 1; off < 256; off <<= 1) {
        int v = (t >= off) ? sh[t - off] : 0;
        __syncthreads();
        sh[t] += v;
        __syncthreads();
    }
    int run = partial[b] + sh[t] - orig;
    for (int i = 0; i < 4; ++i) {
        int idx = base + i;
        if (idx < N) rowptr[idx] = run;
        run += local[i];
    }
    if (b == 0 && t == 0) rowptr[N] = E;
}

__global__ void k_scatter(const int* __restrict__ src, const int* __restrict__ dst,
                          const int* __restrict__ rowptr, int* __restrict__ cur,
                          int* __restrict__ csr_src, int E) {
    for (int e = blockIdx.x * blockDim.x + threadIdx.x; e < E; e += gridDim.x * blockDim.x) {
        int d = dst[e];
        int pos = atomicAdd(&cur[d], 1);
        csr_src[rowptr[d] + pos] = src[e];
    }
}

// ============================================================================
// Fused per-node GAT aggregation: softmax over incoming edges (+self loop),
// weighted gather of xp[src], head mean + bias + ReLU.
// Block = 128 threads = 2 waves; wave h handles head h; lane = channel.
// ============================================================================
__global__ void k_node_gather(const int* __restrict__ rowptr, const int* __restrict__ csr_src,
                              const float* __restrict__ asrc, const float* __restrict__ adst,
                              const float* __restrict__ xp, const float* __restrict__ b,
                              float* __restrict__ hout) {
    int n = blockIdx.x;
    int h = threadIdx.x >> 6, lane = threadIdx.x & 63;
    int row_s = rowptr[n], row_e = rowptr[n + 1];

    float a_dst = adst[n * 2 + h];
    float v_self = lrelu(asrc[n * 2 + h] + a_dst);

    // ---- phase A: max (lanes strided over edges) ----
    float m = v_self;
    for (int e = row_s + lane; e < row_e; e += 64) {
        int s = csr_src[e];
        m = fmaxf(m, lrelu(asrc[s * 2 + h] + a_dst));
    }
    for (int off = 32; off > 0; off >>= 1) m = fmaxf(m, __shfl_xor(m, off, 64));

    // ---- phase B: denominator ----
    float den = (lane == 0) ? __expf(v_self - m) : 0.f;
    for (int e = row_s + lane; e < row_e; e += 64) {
        int s = csr_src[e];
        den += __expf(lrelu(asrc[s * 2 + h] + a_dst) - m);
    }
    for (int off = 32; off > 0; off >>= 1) den += __shfl_xor(den, off, 64);
    float inv = 1.f / (den + 1e-16f);

    // ---- phase C: weighted gather (lane = channel, edges serial) ----
    float acc = __expf(v_self - m) * inv * xp[(size_t)n * 128 + h * 64 + lane];
    for (int e = row_s; e < row_e; ++e) {
        int s = csr_src[e];                         // uniform across wave
        float alpha = __expf(lrelu(asrc[s * 2 + h] + a_dst) - m) * inv;
        acc += alpha * xp[(size_t)s * 128 + h * 64 + lane];
    }

    // ---- head mean + bias + relu ----
    __shared__ float sh[64];
    if (h == 1) sh[lane] = acc;
    __syncthreads();
    if (h == 0) {
        float v = (acc + sh[lane]) * 0.5f + b[lane];
        hout[(size_t)n * 64 + lane] = v > 0.f ? v : 0.f;
    }
}

// climber embed: relu(climber @ Wc + bc), [G,64]
__global__ void k_climber(const float* __restrict__ climber, const float* __restrict__ Wc,
                          const float* __restrict__ bc, float* __restrict__ cemb, int g64) {
    int i = blockIdx.x * blockDim.x + threadIdx.x;
    if (i >= g64) return;
    int g = i >> 6, c = i & 63;
    float acc = bc[c];
    for (int k = 0; k < 4; ++k) acc += climber[g * 4 + k] * Wc[k * 64 + c];
    cemb[i] = acc > 0.f ? acc : 0.f;
}

// final: z=[h2, cemb[batch]] (128) -> relu(z@Wm1+bm1) (64) -> @Wm2+bm2 (4)
__global__ void k_final(const float* __restrict__ h2, const float* __restrict__ cemb,
                        const int* __restrict__ batch, const float* __restrict__ Wm1,
                        const float* __restrict__ bm1, const float* __restrict__ Wm2,
                        const float* __restrict__ bm2, float* __restrict__ out) {
    int n = blockIdx.x, t = threadIdx.x;   // 64 threads
    __shared__ float z[128];
    __shared__ float mbuf[64];
    z[t] = h2[(size_t)n * 64 + t];
    z[64 + t] = cemb[(size_t)batch[n] * 64 + t];
    __syncthreads();
    float acc = bm1[t];
    for (int k = 0; k < 128; ++k) acc += z[k] * Wm1[k * 64 + t];
    mbuf[t] = acc > 0.f ? acc : 0.f;
    __syncthreads();
    if (t < 4) {
        float o = bm2[t];
        for (int k = 0; k < 64; ++k) o += mbuf[k] * Wm2[k * 4 + t];
        out[(size_t)n * 4 + t] = o;
    }
}

extern "C" void kernel_launch(void* const* d_in, const int* in_sizes, int n_in,
                              void* d_out, int out_size, void* d_ws, size_t ws_size,
                              hipStream_t stream) {
    const float* x       = (const float*)d_in[0];
    const int*   ei      = (const int*)  d_in[1];
    const int*   batch   = (const int*)  d_in[2];
    const float* climber = (const float*)d_in[3];
    const float* W1  = (const float*)d_in[4];
    const float* as1 = (const float*)d_in[5];
    const float* ad1 = (const float*)d_in[6];
    const float* b1  = (const float*)d_in[7];
    const float* W2  = (const float*)d_in[8];
    const float* as2 = (const float*)d_in[9];
    const float* ad2 = (const float*)d_in[10];
    const float* b2  = (const float*)d_in[11];
    const float* Wc  = (const float*)d_in[12];
    const float* bc  = (const float*)d_in[13];
    const float* Wm1 = (const float*)d_in[14];
    const float* bm1 = (const float*)d_in[15];
    const float* Wm2 = (const float*)d_in[16];
    const float* bm2 = (const float*)d_in[17];

    const int N  = in_sizes[0] / 6;
    const int E  = in_sizes[1] / 2;
    const int G  = in_sizes[3] / 4;

    const int* srcI = ei;
    const int* dstI = ei + E;

    // ---------------- workspace carve ----------------
    char* base = (char*)d_ws;
    size_t off = 0;
    auto carve = [&](size_t bytes) { void* p = base + off; off += (bytes + 255) & ~size_t(255); return p; };
    float* xp      = (float*)carve((size_t)N * 128 * 4);
    float* hbuf    = (float*)carve((size_t)N * 64 * 4);
    float* asrc    = (float*)carve((size_t)N * 2 * 4);
    float* adst    = (float*)carve((size_t)N * 2 * 4);
    float* cemb    = (float*)carve((size_t)G * 64 * 4);
    int*   deg     = (int*)  carve((size_t)N * 4);
    int*   rowptr  = (int*)  carve((size_t)(N + 1) * 4);
    int*   cur     = (int*)  carve((size_t)N * 4);
    int*   partial = (int*)  carve(4096 * 4);
    int*   csr_src = (int*)  carve((size_t)E * 4);

    const int tpb = 256;
    const int nScanBlk = (N + 1023) / 1024;

    // ---------------- CSR build (shared by both layers) ----------------
    hipMemsetAsync(deg, 0, (size_t)N * 4, stream);
    hipMemsetAsync(cur, 0, (size_t)N * 4, stream);
    k_hist<<<1024, tpb, 0, stream>>>(dstI, deg, E);
    k_scan_partial<<<nScanBlk, tpb, 0, stream>>>(deg, partial, N);
    k_scan_partials<<<1, tpb, 0, stream>>>(partial, nScanBlk);
    k_scan_final<<<nScanBlk, tpb, 0, stream>>>(deg, partial, rowptr, N, E);
    k_scatter<<<1024, tpb, 0, stream>>>(srcI, dstI, rowptr, cur, csr_src, E);

    // ---------------- layer 1 ----------------
    k_xp_att<<<N, 128, 0, stream>>>(x, W1, as1, ad1, xp, asrc, adst, 6);
    k_node_gather<<<N, 128, 0, stream>>>(rowptr, csr_src, asrc, adst, xp, b1, hbuf);

    // ---------------- layer 2 ----------------
    k_xp_att<<<N, 128, 0, stream>>>(hbuf, W2, as2, ad2, xp, asrc, adst, 64);
    k_node_gather<<<N, 128, 0, stream>>>(rowptr, csr_src, asrc, adst, xp, b2, hbuf);

    // ---------------- classifier ----------------
    k_climber<<<(G * 64 + tpb - 1) / tpb, tpb, 0, stream>>>(climber, Wc, bc, cemb, G * 64);
    k_final<<<N, 64, 0, stream>>>(hbuf, cemb, batch, Wm1, bm1, Wm2, bm2, (float*)d_out);
}

// Round 3
// 746.293 us; speedup vs baseline: 2.0656x; 1.1202x over previous
//
#include <hip/hip_runtime.h>

#define SLOPE 0.2f
#define NEG_INF -3.4e38f

__device__ __forceinline__ float lrelu(float v) { return v >= 0.f ? v : SLOPE * v; }

// ============================================================================
// xp = x @ W  (in_dim -> 128 = 2 heads * 64), plus per-head attention dots.
// ============================================================================
__global__ void k_xp_att(const float* __restrict__ x, const float* __restrict__ W,
                         const float* __restrict__ as_, const float* __restrict__ ad_,
                         float* __restrict__ xp, float* __restrict__ asrc,
                         float* __restrict__ adst, int in_dim) {
    int n = blockIdx.x;
    int c = threadIdx.x;               // 0..127
    __shared__ float xr[64];
    if (c < in_dim) xr[c] = x[(size_t)n * in_dim + c];
    __syncthreads();
    float acc = 0.f;
    for (int k = 0; k < in_dim; ++k) acc += xr[k] * W[k * 128 + c];
    xp[(size_t)n * 128 + c] = acc;
    int h = c >> 6, ch = c & 63;
    float ps = acc * as_[h * 64 + ch];
    float pd = acc * ad_[h * 64 + ch];
    for (int off = 32; off > 0; off >>= 1) {
        ps += __shfl_down(ps, off, 64);
        pd += __shfl_down(pd, off, 64);
    }
    if (ch == 0) { asrc[n * 2 + h] = ps; adst[n * 2 + h] = pd; }
}

// ============================================================================
// CSR build: histogram -> exclusive scan -> scatter (counting sort by dst)
// ============================================================================
__global__ void k_hist(const int* __restrict__ dst, int* __restrict__ deg, int E) {
    for (int e = blockIdx.x * blockDim.x + threadIdx.x; e < E; e += gridDim.x * blockDim.x)
        atomicAdd(&deg[dst[e]], 1);
}

__global__ void k_scan_partial(const int* __restrict__ deg, int* __restrict__ partial, int N) {
    int b = blockIdx.x, t = threadIdx.x;
    int base = b * 1024 + t * 4;
    int s = 0;
    for (int i = 0; i < 4; ++i) { int idx = base + i; if (idx < N) s += deg[idx]; }
    __shared__ int sh[256];
    sh[t] = s; __syncthreads();
    for (int off = 128; off > 0; off >>= 1) { if (t < off) sh[t] += sh[t + off]; __syncthreads(); }
    if (t == 0) partial[b] = sh[0];
}

__global__ void k_scan_partials(int* __restrict__ partial, int nb) {
    __shared__ int sh[256];
    __shared__ int carry;
    int t = threadIdx.x;
    if (t == 0) carry = 0;
    __syncthreads();
    for (int base = 0; base < nb; base += 256) {
        int idx = base + t;
        int orig = (idx < nb) ? partial[idx] : 0;
        sh[t] = orig; __syncthreads();
        for (int off = 1; off < 256; off <<= 1) {
            int v = (t >= off) ? sh[t - off] : 0;
            __syncthreads();
            sh[t] += v;
            __syncthreads();
        }
        if (idx < nb) partial[idx] = carry + sh[t] - orig;
        __syncthreads();
        if (t == 0) carry += sh[255];
        __syncthreads();
    }
}

__global__ void k_scan_final(const int* __restrict__ deg, const int* __restrict__ partial,
                             int* __restrict__ rowptr, int N, int E) {
    int b = blockIdx.x, t = threadIdx.x;
    int base = b * 1024 + t * 4;
    int local[4]; int s = 0;
    for (int i = 0; i < 4; ++i) { int idx = base + i; local[i] = (idx < N) ? deg[idx] : 0; s += local[i]; }
    __shared__ int sh[256];
    int orig = s;
    sh[t] = s; __syncthreads();
    for (int off = 1; off < 256; off <<= 1) {
        int v = (t >= off) ? sh[t - off] : 0;
        __syncthreads();
        sh[t] += v;
        __syncthreads();
    }
    int run = partial[b] + sh[t] - orig;
    for (int i = 0; i < 4; ++i) {
        int idx = base + i;
        if (idx < N) rowptr[idx] = run;
        run += local[i];
    }
    if (b == 0 && t == 0) rowptr[N] = E;
}

__global__ void k_scatter(const int* __restrict__ src, const int* __restrict__ dst,
                          const int* __restrict__ rowptr, int* __restrict__ cur,
                          int* __restrict__ csr_src, int E) {
    for (int e = blockIdx.x * blockDim.x + threadIdx.x; e < E; e += gridDim.x * blockDim.x) {
        int d = dst[e];
        int pos = atomicAdd(&cur[d], 1);
        csr_src[rowptr[d] + pos] = src[e];
    }
}

// ============================================================================
// Per-node softmax -> alpha planes. Block=128 (wave h = head h).
// alpha layout: [2][E] head-major; aself: [2][N].
// Fast path deg<=64: one edge per lane, single pass.
// ============================================================================
__global__ void k_node_alpha(const int* __restrict__ rowptr, const int* __restrict__ csr_src,
                             const float* __restrict__ asrc, const float* __restrict__ adst,
                             float* __restrict__ alpha, float* __restrict__ aself,
                             int N, int E) {
    int n = blockIdx.x;
    int h = threadIdx.x >> 6, lane = threadIdx.x & 63;
    int rs = rowptr[n], re = rowptr[n + 1], cnt = re - rs;
    float a_dst = adst[n * 2 + h];
    float v_self = lrelu(asrc[n * 2 + h] + a_dst);

    if (cnt <= 64) {
        float v = NEG_INF;
        if (lane < cnt) {
            int s = csr_src[rs + lane];
            v = lrelu(asrc[s * 2 + h] + a_dst);
        }
        float m = fmaxf(v, v_self);
        for (int off = 32; off > 0; off >>= 1) m = fmaxf(m, __shfl_xor(m, off, 64));
        float ex = (lane < cnt) ? __expf(v - m) : 0.f;
        float exs = __expf(v_self - m);
        float den = ex + (lane == 0 ? exs : 0.f);
        for (int off = 32; off > 0; off >>= 1) den += __shfl_xor(den, off, 64);
        float inv = 1.f / (den + 1e-16f);
        if (lane < cnt) alpha[(size_t)h * E + rs + lane] = ex * inv;
        if (lane == 0) aself[(size_t)h * N + n] = exs * inv;
    } else {
        float m = v_self;
        for (int e = rs + lane; e < re; e += 64) {
            int s = csr_src[e];
            m = fmaxf(m, lrelu(asrc[s * 2 + h] + a_dst));
        }
        for (int off = 32; off > 0; off >>= 1) m = fmaxf(m, __shfl_xor(m, off, 64));
        float den = (lane == 0) ? __expf(v_self - m) : 0.f;
        for (int e = rs + lane; e < re; e += 64) {
            int s = csr_src[e];
            den += __expf(lrelu(asrc[s * 2 + h] + a_dst) - m);
        }
        for (int off = 32; off > 0; off >>= 1) den += __shfl_xor(den, off, 64);
        float inv = 1.f / (den + 1e-16f);
        for (int e = rs + lane; e < re; e += 64) {
            int s = csr_src[e];
            alpha[(size_t)h * E + e] = __expf(lrelu(asrc[s * 2 + h] + a_dst) - m) * inv;
        }
        if (lane == 0) aself[(size_t)h * N + n] = __expf(v_self - m) * inv;
    }
}

// ============================================================================
// Weighted gather: block=128 (wave h = head h); 4 lane-groups of 16 stream
// 4 edges concurrently with float4 loads; 2-stage shuffle combine; head mean.
// ============================================================================
__global__ void k_gather4(const int* __restrict__ rowptr, const int* __restrict__ csr_src,
                          const float* __restrict__ alpha, const float* __restrict__ aself,
                          const float* __restrict__ xp, const float* __restrict__ b,
                          float* __restrict__ hout, int N, int E) {
    int n = blockIdx.x;
    int h = threadIdx.x >> 6, lane = threadIdx.x & 63;
    int g = lane >> 4, l = lane & 15;
    int rs = rowptr[n], re = rowptr[n + 1];
    const float4* xp4 = (const float4*)xp;   // 32 float4 per node row

    float4 acc = make_float4(0.f, 0.f, 0.f, 0.f);
    if (g == 0) {
        float a0 = aself[(size_t)h * N + n];
        float4 v = xp4[(size_t)n * 32 + h * 16 + l];
        acc.x = a0 * v.x; acc.y = a0 * v.y; acc.z = a0 * v.z; acc.w = a0 * v.w;
    }
    for (int e = rs + g; e < re; e += 4) {
        int s = csr_src[e];
        float a = alpha[(size_t)h * E + e];
        float4 v = xp4[(size_t)s * 32 + h * 16 + l];
        acc.x += a * v.x; acc.y += a * v.y; acc.z += a * v.z; acc.w += a * v.w;
    }
    // combine the 4 edge-groups (lanes l, l+16, l+32, l+48)
    for (int off = 16; off <= 32; off <<= 1) {
        acc.x += __shfl_xor(acc.x, off, 64);
        acc.y += __shfl_xor(acc.y, off, 64);
        acc.z += __shfl_xor(acc.z, off, 64);
        acc.w += __shfl_xor(acc.w, off, 64);
    }
    __shared__ float4 shv[16];
    if (h == 1 && g == 0) shv[l] = acc;
    __syncthreads();
    if (h == 0 && g == 0) {
        float4 o = shv[l];
        float4 bb = ((const float4*)b)[l];
        float4 r;
        r.x = fmaxf((acc.x + o.x) * 0.5f + bb.x, 0.f);
        r.y = fmaxf((acc.y + o.y) * 0.5f + bb.y, 0.f);
        r.z = fmaxf((acc.z + o.z) * 0.5f + bb.z, 0.f);
        r.w = fmaxf((acc.w + o.w) * 0.5f + bb.w, 0.f);
        ((float4*)hout)[(size_t)n * 16 + l] = r;
    }
}

// climber embed: relu(climber @ Wc + bc), [G,64]
__global__ void k_climber(const float* __restrict__ climber, const float* __restrict__ Wc,
                          const float* __restrict__ bc, float* __restrict__ cemb, int g64) {
    int i = blockIdx.x * blockDim.x + threadIdx.x;
    if (i >= g64) return;
    int g = i >> 6, c = i & 63;
    float acc = bc[c];
    for (int k = 0; k < 4; ++k) acc += climber[g * 4 + k] * Wc[k * 64 + c];
    cemb[i] = acc > 0.f ? acc : 0.f;
}

// final MLP: split-K across 2 waves, wave-reduce output stage.
__global__ void k_final(const float* __restrict__ h2, const float* __restrict__ cemb,
                        const int* __restrict__ batch, const float* __restrict__ Wm1,
                        const float* __restrict__ bm1, const float* __restrict__ Wm2,
                        const float* __restrict__ bm2, float* __restrict__ out) {
    int n = blockIdx.x, t = threadIdx.x;   // 128 threads
    int w = t >> 6, lane = t & 63;
    __shared__ float z[128];
    __shared__ float part[64];
    z[t] = (t < 64) ? h2[(size_t)n * 64 + t]
                    : cemb[(size_t)batch[n] * 64 + (t - 64)];
    __syncthreads();
    float acc = 0.f;
    #pragma unroll 8
    for (int k = 0; k < 64; ++k)
        acc += z[w * 64 + k] * Wm1[(w * 64 + k) * 64 + lane];
    if (w == 1) part[lane] = acc;
    __syncthreads();
    if (w == 0) {
        float m = acc + part[lane] + bm1[lane];
        m = m > 0.f ? m : 0.f;
        float4 wr = ((const float4*)Wm2)[lane];      // Wm2[lane][0..3]
        float4 p;
        p.x = m * wr.x; p.y = m * wr.y; p.z = m * wr.z; p.w = m * wr.w;
        for (int off = 32; off > 0; off >>= 1) {
            p.x += __shfl_down(p.x, off, 64);
            p.y += __shfl_down(p.y, off, 64);
            p.z += __shfl_down(p.z, off, 64);
            p.w += __shfl_down(p.w, off, 64);
        }
        if (lane == 0) {
            float4 bb = *((const float4*)bm2);
            float4 o;
            o.x = p.x + bb.x; o.y = p.y + bb.y; o.z = p.z + bb.z; o.w = p.w + bb.w;
            ((float4*)out)[n] = o;
        }
    }
}

extern "C" void kernel_launch(void* const* d_in, const int* in_sizes, int n_in,
                              void* d_out, int out_size, void* d_ws, size_t ws_size,
                              hipStream_t stream) {
    const float* x       = (const float*)d_in[0];
    const int*   ei      = (const int*)  d_in[1];
    const int*   batch   = (const int*)  d_in[2];
    const float* climber = (const float*)d_in[3];
    const float* W1  = (const float*)d_in[4];
    const float* as1 = (const float*)d_in[5];
    const float* ad1 = (const float*)d_in[6];
    const float* b1  = (const float*)d_in[7];
    const float* W2  = (const float*)d_in[8];
    const float* as2 = (const float*)d_in[9];
    const float* ad2 = (const float*)d_in[10];
    const float* b2  = (const float*)d_in[11];
    const float* Wc  = (const float*)d_in[12];
    const float* bc  = (const float*)d_in[13];
    const float* Wm1 = (const float*)d_in[14];
    const float* bm1 = (const float*)d_in[15];
    const float* Wm2 = (const float*)d_in[16];
    const float* bm2 = (const float*)d_in[17];

    const int N  = in_sizes[0] / 6;
    const int E  = in_sizes[1] / 2;
    const int G  = in_sizes[3] / 4;

    const int* srcI = ei;
    const int* dstI = ei + E;

    // ---------------- workspace carve ----------------
    char* base = (char*)d_ws;
    size_t off = 0;
    auto carve = [&](size_t bytes) { void* p = base + off; off += (bytes + 255) & ~size_t(255); return p; };
    float* xp      = (float*)carve((size_t)N * 128 * 4);
    float* hbuf    = (float*)carve((size_t)N * 64 * 4);
    float* asrc    = (float*)carve((size_t)N * 2 * 4);
    float* adst    = (float*)carve((size_t)N * 2 * 4);
    float* cemb    = (float*)carve((size_t)G * 64 * 4);
    int*   deg     = (int*)  carve((size_t)N * 4);
    int*   rowptr  = (int*)  carve((size_t)(N + 1) * 4);
    int*   cur     = (int*)  carve((size_t)N * 4);
    int*   partial = (int*)  carve(4096 * 4);
    int*   csr_src = (int*)  carve((size_t)E * 4);
    float* alpha   = (float*)carve((size_t)E * 2 * 4);
    float* aself   = (float*)carve((size_t)N * 2 * 4);

    const int tpb = 256;
    const int nScanBlk = (N + 1023) / 1024;

    // ---------------- CSR build (shared by both layers) ----------------
    hipMemsetAsync(deg, 0, (size_t)N * 4, stream);
    hipMemsetAsync(cur, 0, (size_t)N * 4, stream);
    k_hist<<<1024, tpb, 0, stream>>>(dstI, deg, E);
    k_scan_partial<<<nScanBlk, tpb, 0, stream>>>(deg, partial, N);
    k_scan_partials<<<1, tpb, 0, stream>>>(partial, nScanBlk);
    k_scan_final<<<nScanBlk, tpb, 0, stream>>>(deg, partial, rowptr, N, E);
    k_scatter<<<1024, tpb, 0, stream>>>(srcI, dstI, rowptr, cur, csr_src, E);

    // ---------------- layer 1 ----------------
    k_xp_att<<<N, 128, 0, stream>>>(x, W1, as1, ad1, xp, asrc, adst, 6);
    k_node_alpha<<<N, 128, 0, stream>>>(rowptr, csr_src, asrc, adst, alpha, aself, N, E);
    k_gather4<<<N, 128, 0, stream>>>(rowptr, csr_src, alpha, aself, xp, b1, hbuf, N, E);

    // ---------------- layer 2 ----------------
    k_xp_att<<<N, 128, 0, stream>>>(hbuf, W2, as2, ad2, xp, asrc, adst, 64);
    k_node_alpha<<<N, 128, 0, stream>>>(rowptr, csr_src, asrc, adst, alpha, aself, N, E);
    k_gather4<<<N, 128, 0, stream>>>(rowptr, csr_src, alpha, aself, xp, b2, hbuf, N, E);

    // ---------------- classifier ----------------
    k_climber<<<(G * 64 + tpb - 1) / tpb, tpb, 0, stream>>>(climber, Wc, bc, cemb, G * 64);
    k_final<<<N, 128, 0, stream>>>(hbuf, cemb, batch, Wm1, bm1, Wm2, bm2, (float*)d_out);
}